// Round 1
// baseline (371.354 us; speedup 1.0000x reference)
//
#include <hip/hip_runtime.h>

#define BB 4
#define CC 5
#define HH 200
#define DKk 20
#define DI 400
#define NPOS (BB*CC*HH)   // 4000
#define SEGS 4
#define NSEG (DI/SEGS)    // 100

// ---------------------------------------------------------------------------
// Kernel 1: projections (all fp32).
//   q/k/v[pos,d] = sum_n X[pos,n,d]*W[n] + b   (N=400, row stride 20 floats)
//   c[pos,d]     = sum_n cdd[pos,n,d]*W1[n]+b1 (N=20)
// R5: the N-reduction is split 4-ways across adjacent lanes (seg = lane&3,
// 100 rows each) and combined with 2 shfl_xor. 320000 threads -> 1250 blocks,
// ~4.9 waves/SIMD (was 1.2): restores TLP latency hiding + kills the 2x
// block-imbalance tail (313 blocks on 256 CUs). W staged in LDS because its
// index is now per-lane (seg-dependent), not wave-uniform.
// ---------------------------------------------------------------------------
__global__ __launch_bounds__(256, 1) void proj_kernel(
    const float* __restrict__ Q,
    const float* __restrict__ K,
    const float* __restrict__ V,
    const float* __restrict__ cdd,
    const float* __restrict__ W,
    const float* __restrict__ bptr,
    const float* __restrict__ W1,
    const float* __restrict__ b1ptr,
    float* __restrict__ proj)   // [4][NPOS][20] : q,k,v,c
{
    __shared__ float sW[DI];
    __shared__ float sW1[DKk];
    for (int i = threadIdx.x; i < DI; i += 256) sW[i] = W[i];
    if (threadIdx.x < DKk) sW1[threadIdx.x] = W1[threadIdx.x];
    __syncthreads();

    int tg     = blockIdx.x * 256 + threadIdx.x;  // 0..319999, exact grid
    int seg    = tg & 3;          // n-segment 0..3 (lane bits 0..1)
    int pq     = tg >> 2;         // 0..79999
    int quad   = pq % 5;          // d-quad 0..4
    int pg     = pq / 5;          // 0..15999
    int tensor = pg / NPOS;       // 0..3
    int pos    = pg % NPOS;

    float a0 = 0.f, a1 = 0.f, a2 = 0.f, a3 = 0.f;

    if (tensor < 3) {
        const float* base = (tensor == 0) ? Q : (tensor == 1) ? K : V;
        const float* src  = base + (size_t)pos * (DI * DKk) + quad * 4;
        const int n0 = seg * NSEG;

        // 6 batches of 16 deep + tail of 4 (100 rows per seg)
        for (int ii = 0; ii < 96; ii += 16) {
            float4 x[16];
            #pragma unroll
            for (int j = 0; j < 16; ++j)
                x[j] = *reinterpret_cast<const float4*>(src + (size_t)(n0 + ii + j) * DKk);
            #pragma unroll
            for (int j = 0; j < 16; ++j) {
                float wn = sW[n0 + ii + j];
                a0 += wn * x[j].x;
                a1 += wn * x[j].y;
                a2 += wn * x[j].z;
                a3 += wn * x[j].w;
            }
        }
        {
            float4 x[4];
            #pragma unroll
            for (int j = 0; j < 4; ++j)
                x[j] = *reinterpret_cast<const float4*>(src + (size_t)(n0 + 96 + j) * DKk);
            #pragma unroll
            for (int j = 0; j < 4; ++j) {
                float wn = sW[n0 + 96 + j];
                a0 += wn * x[j].x;
                a1 += wn * x[j].y;
                a2 += wn * x[j].z;
                a3 += wn * x[j].w;
            }
        }
    } else {
        const float* src = cdd + (size_t)pos * (DKk * DKk) + quad * 4;
        const int n0 = seg * 5;   // 5 rows per seg
        float4 x[5];
        #pragma unroll
        for (int j = 0; j < 5; ++j)
            x[j] = *reinterpret_cast<const float4*>(src + (size_t)(n0 + j) * DKk);
        #pragma unroll
        for (int j = 0; j < 5; ++j) {
            float wn = sW1[n0 + j];
            a0 += wn * x[j].x;
            a1 += wn * x[j].y;
            a2 += wn * x[j].z;
            a3 += wn * x[j].w;
        }
    }

    // combine the 4 n-segments (adjacent lanes; all lanes active here)
    a0 += __shfl_xor(a0, 1); a0 += __shfl_xor(a0, 2);
    a1 += __shfl_xor(a1, 1); a1 += __shfl_xor(a1, 2);
    a2 += __shfl_xor(a2, 1); a2 += __shfl_xor(a2, 2);
    a3 += __shfl_xor(a3, 1); a3 += __shfl_xor(a3, 2);

    if (seg == 0) {
        float bias = (tensor < 3) ? bptr[0] : b1ptr[0];
        float4 o; o.x = a0 + bias; o.y = a1 + bias; o.z = a2 + bias; o.w = a3 + bias;
        // seg-0 lanes of a wave hit 16 consecutive float4 -> 256B contiguous
        *reinterpret_cast<float4*>(proj + ((size_t)tensor * NPOS + pos) * DKk + quad * 4) = o;
    }
}

// ---------------------------------------------------------------------------
// Kernel 2: attention WITH fused normalization. Per (b,c):
//   scores[h,g] = (q[h].k[g] + k[h].c[g])/sqrt(20); s = exp(scores)
// s values stay in registers (7/thread); rowsum via shfl_xor butterfly gives
// every lane the sum, so normalized attn is written directly (norm_kernel
// eliminated: -1 launch, -6.4MB HBM round trip).
// Grid: 20 bc * 25 row-tiles = 500 blocks; 256 thr = 8 rows * 32 subs.
// ---------------------------------------------------------------------------
__global__ __launch_bounds__(256) void attn_kernel(
    const float* __restrict__ proj,
    float* __restrict__ attn_out,  // [NPOS][200] fp32, normalized (in d_out)
    float* __restrict__ ctx_out)   // [NPOS][20] fp32 (d_out head)
{
    __shared__ float sk[HH * DKk];
    __shared__ float sc[HH * DKk];
    __shared__ float sv[HH * DKk];

    int bc   = blockIdx.x / 25;
    int tile = blockIdx.x % 25;
    int t    = threadIdx.x;

    const float* kp = proj + ((size_t)1 * NPOS + bc * HH) * DKk;
    const float* vp = proj + ((size_t)2 * NPOS + bc * HH) * DKk;
    const float* cp = proj + ((size_t)3 * NPOS + bc * HH) * DKk;

    for (int i = t; i < HH * DKk / 4; i += 256) {
        reinterpret_cast<float4*>(sk)[i] = reinterpret_cast<const float4*>(kp)[i];
        reinterpret_cast<float4*>(sc)[i] = reinterpret_cast<const float4*>(cp)[i];
        reinterpret_cast<float4*>(sv)[i] = reinterpret_cast<const float4*>(vp)[i];
    }
    __syncthreads();

    int row = t >> 5;            // 0..7
    int sub = t & 31;            // 0..31
    int h   = tile * 8 + row;    // 0..199
    int rowIdx = bc * HH + h;

    const float* qr_p = proj + ((size_t)0 * NPOS + rowIdx) * DKk;
    const float* kr_p = proj + ((size_t)1 * NPOS + rowIdx) * DKk;
    float qr[DKk], kr[DKk];
    #pragma unroll
    for (int i = 0; i < 5; ++i) {
        float4 a = reinterpret_cast<const float4*>(qr_p)[i];
        qr[4*i] = a.x; qr[4*i+1] = a.y; qr[4*i+2] = a.z; qr[4*i+3] = a.w;
        float4 b = reinterpret_cast<const float4*>(kr_p)[i];
        kr[4*i] = b.x; kr[4*i+1] = b.y; kr[4*i+2] = b.z; kr[4*i+3] = b.w;
    }

    const float inv_sqrt = 0.22360679774997896f;  // 1/sqrt(20)
    float ctx[DKk];
    #pragma unroll
    for (int d = 0; d < DKk; ++d) ctx[d] = 0.f;
    float rs = 0.f;
    float sreg[7];   // s values kept in registers (static indexing via unroll)

    #pragma unroll
    for (int kk = 0; kk < 7; ++kk) {
        int g = sub + 32 * kk;
        float s = 0.f;
        if (g < HH) {
            float dot = 0.f;
            #pragma unroll
            for (int i = 0; i < 5; ++i) {
                float4 kg = reinterpret_cast<const float4*>(sk + g * DKk)[i];
                float4 cg = reinterpret_cast<const float4*>(sc + g * DKk)[i];
                dot += qr[4*i]   * kg.x + qr[4*i+1] * kg.y
                     + qr[4*i+2] * kg.z + qr[4*i+3] * kg.w;
                dot += kr[4*i]   * cg.x + kr[4*i+1] * cg.y
                     + kr[4*i+2] * cg.z + kr[4*i+3] * cg.w;
            }
            s = __expf(dot * inv_sqrt);
            #pragma unroll
            for (int i = 0; i < 5; ++i) {
                float4 vg = reinterpret_cast<const float4*>(sv + g * DKk)[i];
                ctx[4*i]   += s * vg.x;
                ctx[4*i+1] += s * vg.y;
                ctx[4*i+2] += s * vg.z;
                ctx[4*i+3] += s * vg.w;
            }
        }
        sreg[kk] = s;
        rs += s;
    }

    // rowsum: butterfly so ALL 32 lanes of the row hold the total
    #pragma unroll
    for (int off = 16; off >= 1; off >>= 1)
        rs += __shfl_xor(rs, off, 32);
    float inv = 1.0f / (rs + 1e-8f);

    // context reduce to sub==0
    #pragma unroll
    for (int off = 16; off >= 1; off >>= 1) {
        #pragma unroll
        for (int d = 0; d < DKk; ++d)
            ctx[d] += __shfl_down(ctx[d], (unsigned)off, 32);
    }

    if (sub == 0) {
        float* co = ctx_out + (size_t)rowIdx * DKk;
        #pragma unroll
        for (int i = 0; i < 5; ++i) {
            float4 o;
            o.x = ctx[4*i]   * inv;
            o.y = ctx[4*i+1] * inv;
            o.z = ctx[4*i+2] * inv;
            o.w = ctx[4*i+3] * inv;
            reinterpret_cast<float4*>(co)[i] = o;
        }
    }

    // normalized attn straight from registers (coalesced per 32-lane group)
    #pragma unroll
    for (int kk = 0; kk < 7; ++kk) {
        int g = sub + 32 * kk;
        if (g < HH)
            attn_out[(size_t)rowIdx * HH + g] = sreg[kk] * inv;
    }
}

extern "C" void kernel_launch(void* const* d_in, const int* in_sizes, int n_in,
                              void* d_out, int out_size, void* d_ws, size_t ws_size,
                              hipStream_t stream) {
    const float* Q   = (const float*)d_in[0];
    const float* K   = (const float*)d_in[1];
    const float* V   = (const float*)d_in[2];
    const float* cdd = (const float*)d_in[3];
    const float* W   = (const float*)d_in[4];
    const float* b   = (const float*)d_in[5];
    const float* W1  = (const float*)d_in[6];
    const float* b1  = (const float*)d_in[7];
    // d_in[8] = d_k (int) — compile-time constant 20

    float* proj = (float*)d_ws;           // 4*4000*20 = 320000 floats = 1.28 MB

    float* out      = (float*)d_out;
    float* ctx_out  = out;                // 80000 fp32 (context)
    float* attn_out = out + 80000;        // 800000 fp32 (attn)

    // 4 tensors * NPOS * 5 quads * 4 segs = 320000 threads = exactly 1250 blocks
    proj_kernel<<<(4 * NPOS * 5 * SEGS) / 256, 256, 0, stream>>>(
        Q, K, V, cdd, W, b, W1, b1, proj);
    attn_kernel<<<CC * BB * 25, 256, 0, stream>>>(proj, attn_out, ctx_out);
}